// Round 2
// baseline (194.924 us; speedup 1.0000x reference)
//
#include <hip/hip_runtime.h>
#include <stdint.h>

typedef unsigned short ushort_t;
typedef __bf16 bf16x8 __attribute__((ext_vector_type(8)));
typedef float f32x4 __attribute__((ext_vector_type(4)));
typedef unsigned short us8 __attribute__((ext_vector_type(8)));
typedef unsigned short us4v __attribute__((ext_vector_type(4)));

__device__ __forceinline__ float bf2f(ushort_t u) {
  union { uint32_t u; float f; } v; v.u = ((uint32_t)u) << 16; return v.f;
}
__device__ __forceinline__ ushort_t f2bf(float f) {
  union { float f; uint32_t u; } v; v.f = f;
  uint32_t u = v.u;
  uint32_t r = (u + 0x7FFFu + ((u >> 16) & 1u)) >> 16;  // RNE
  return (ushort_t)r;
}
__device__ __forceinline__ void gload_lds16(const void* g, void* l) {
  __builtin_amdgcn_global_load_lds(
      (const __attribute__((address_space(1))) void*)g,
      (__attribute__((address_space(3))) void*)l, 16, 0, 0);
}

template <typename T> __device__ __forceinline__ T to_out(float f);
template <> __device__ __forceinline__ ushort_t to_out<ushort_t>(float f) { return f2bf(f); }
template <> __device__ __forceinline__ float to_out<float>(float f) { return f; }

// ---------------------------------------------------------------------------
// fp32 -> bf16 convert (vectorized, grid-stride)
// ---------------------------------------------------------------------------
__global__ void f2b_kernel(const float* __restrict__ in, ushort_t* __restrict__ out, int n4) {
  int i = blockIdx.x * blockDim.x + threadIdx.x;
  int stride = gridDim.x * blockDim.x;
  for (; i < n4; i += stride) {
    float4 v = ((const float4*)in)[i];
    us4v o;
    o[0] = f2bf(v.x); o[1] = f2bf(v.y); o[2] = f2bf(v.z); o[3] = f2bf(v.w);
    ((us4v*)out)[i] = o;
  }
}

// ---------------------------------------------------------------------------
// GEMM: C[M][N] = A[M][K] @ W[N][K]^T (+bias), bf16 in, fp32 accum, OT out.
// 128x128 tile, BK=64, 256 threads (4 waves, 2x2 of 64x64).
// LDS tiles linear [128][64] bf16 with XOR swizzle (chunk ^= row&7) applied
// on the GLOBAL source (store side) and on ds_read addresses (read side).
// ---------------------------------------------------------------------------
template<bool BIAS, typename OT>
__global__ __launch_bounds__(256, 2) void gemm_bt(
    const ushort_t* __restrict__ A, const ushort_t* __restrict__ W,
    const float* __restrict__ bias, OT* __restrict__ C,
    int M, int N, int K)
{
  __shared__ ushort_t As[128 * 64];
  __shared__ ushort_t Bs[128 * 64];
  const int t = threadIdx.x;
  const int w = t >> 6, lane = t & 63;
  const int lg = lane >> 4, lc = lane & 15;
  const int rowbase = blockIdx.y * 128;
  const int colbase = blockIdx.x * 128;
  const int wr = (w >> 1) * 64, wc = (w & 1) * 64;

  f32x4 acc[4][4] = {};
  const int nkt = K >> 6;

  for (int kt = 0; kt < nkt; ++kt) {
    // ---- stage A,B tiles (4 x 16B issues each per thread) ----
#pragma unroll
    for (int i = 0; i < 4; ++i) {
      int off = (i * 256 + t) * 16;          // byte offset in tile
      int row = off >> 7;                    // 128 B per row
      int cb  = off & 127;
      int ec  = cb ^ ((row & 7) << 4);       // pre-swizzled source column
      gload_lds16(A + (size_t)(rowbase + row) * K + kt * 64 + (ec >> 1),
                  (char*)As + off);
      gload_lds16(W + (size_t)(colbase + row) * K + kt * 64 + (ec >> 1),
                  (char*)Bs + off);
    }
    __syncthreads();
    // ---- compute ----
#pragma unroll
    for (int kk = 0; kk < 2; ++kk) {
      bf16x8 af[4], bf[4];
#pragma unroll
      for (int m = 0; m < 4; ++m) {
        int row = wr + m * 16 + lc;
        int kb  = (lg * 16 + kk * 64) ^ ((row & 7) << 4);
        af[m] = *(const bf16x8*)((const char*)As + row * 128 + kb);
        int col = wc + m * 16 + lc;
        int kb2 = (lg * 16 + kk * 64) ^ ((col & 7) << 4);
        bf[m] = *(const bf16x8*)((const char*)Bs + col * 128 + kb2);
      }
#pragma unroll
      for (int m = 0; m < 4; ++m)
#pragma unroll
        for (int n = 0; n < 4; ++n)
          acc[m][n] = __builtin_amdgcn_mfma_f32_16x16x32_bf16(af[m], bf[n],
                                                              acc[m][n], 0, 0, 0);
    }
    __syncthreads();
  }

  // ---- epilogue: D layout col=lane&15, row=(lane>>4)*4+j ----
#pragma unroll
  for (int m = 0; m < 4; ++m) {
    int r0 = rowbase + wr + m * 16 + lg * 4;
#pragma unroll
    for (int n = 0; n < 4; ++n) {
      int c0 = colbase + wc + n * 16 + lc;
      float bv = 0.f;
      if (BIAS) bv = bias[c0];
#pragma unroll
      for (int j = 0; j < 4; ++j)
        C[(size_t)(r0 + j) * N + c0] = to_out<OT>(acc[m][n][j] + bv);
    }
  }
}

// ---------------------------------------------------------------------------
// Flash attention, one block per (b, h, q-tile of 128). 4 waves x 32 q-rows.
// qkv: [4096][3072] bf16 (cols 0..1023 Q, 1024..2047 K, 2048..3071 V;
// head h = cols h*64..h*64+63). aout: [4096][1024] bf16.
// ---------------------------------------------------------------------------
__device__ __forceinline__ void stage_kv(const ushort_t* __restrict__ Kg,
                                         const ushort_t* __restrict__ Vg,
                                         ushort_t* Ks, ushort_t* Vt,
                                         int kt, int t) {
  // K tile [64][64], swizzled like GEMM tiles (2 x 16B issues)
#pragma unroll
  for (int i = 0; i < 2; ++i) {
    int off = (i * 256 + t) * 16;
    int row = off >> 7;
    int cb  = off & 127;
    int ec  = cb ^ ((row & 7) << 4);
    gload_lds16(Kg + (size_t)(kt * 64 + row) * 3072 + (ec >> 1),
                (char*)Ks + off);
  }
  // V tile transposed into Vt[d][kv], row stride 72 elems (pad vs conflicts)
#pragma unroll
  for (int i = 0; i < 2; ++i) {
    int u  = i * 256 + t;
    int r  = u >> 3;            // kv row
    int c0 = (u & 7) * 8;       // d base
    us8 v = *(const us8*)(Vg + (size_t)(kt * 64 + r) * 3072 + c0);
#pragma unroll
    for (int j = 0; j < 8; ++j)
      Vt[(c0 + j) * 72 + r] = v[j];
  }
}

__global__ __launch_bounds__(256, 2) void attn_fwd(
    const ushort_t* __restrict__ qkv, ushort_t* __restrict__ aout)
{
  __shared__ ushort_t Qs[128 * 64];
  __shared__ ushort_t Ks[64 * 64];
  __shared__ ushort_t Vt[64 * 72];
  __shared__ ushort_t Ps[4][32 * 72];

  const int t = threadIdx.x, w = t >> 6, lane = t & 63;
  const int lg = lane >> 4, lc = lane & 15;
  const int qt = blockIdx.x, bh = blockIdx.y;
  const int b = bh >> 4, h = bh & 15;

  const ushort_t* Qg = qkv + (size_t)(b * 2048) * 3072 + h * 64;
  const ushort_t* Kg = Qg + 1024;
  const ushort_t* Vg = Qg + 2048;

  // stage Q tile [128][64] linear (read once -> no swizzle needed)
#pragma unroll
  for (int i = 0; i < 4; ++i) {
    int off = (i * 256 + t) * 16;
    int row = off >> 7;
    int cb  = off & 127;
    gload_lds16(Qg + (size_t)(qt * 128 + row) * 3072 + (cb >> 1),
                (char*)Qs + off);
  }
  stage_kv(Kg, Vg, Ks, Vt, 0, t);
  __syncthreads();

  // hoist Q fragments to registers: wave rows [w*32, w*32+32)
  bf16x8 qf[2][2];
#pragma unroll
  for (int m = 0; m < 2; ++m)
#pragma unroll
    for (int kk = 0; kk < 2; ++kk) {
      int row = w * 32 + m * 16 + lc;
      qf[m][kk] = *(const bf16x8*)((const char*)Qs + row * 128 + lg * 16 + kk * 64);
    }

  f32x4 oacc[2][4] = {};
  float mrow[2][4], lrow[2][4];
#pragma unroll
  for (int m = 0; m < 2; ++m)
#pragma unroll
    for (int j = 0; j < 4; ++j) { mrow[m][j] = -INFINITY; lrow[m][j] = 0.f; }

  ushort_t* Pw = &Ps[w][0];
  const float SC = 0.125f * 1.44269504088896f;  // scale * log2(e)

  for (int kt = 0; kt < 32; ++kt) {
    // ---- S = Q @ K^T (per wave: 32 x 64) ----
    f32x4 s[2][4] = {};
#pragma unroll
    for (int kk = 0; kk < 2; ++kk) {
      bf16x8 kf[4];
#pragma unroll
      for (int n = 0; n < 4; ++n) {
        int row = n * 16 + lc;
        int kb  = (lg * 16 + kk * 64) ^ ((row & 7) << 4);
        kf[n] = *(const bf16x8*)((const char*)Ks + row * 128 + kb);
      }
#pragma unroll
      for (int m = 0; m < 2; ++m)
#pragma unroll
        for (int n = 0; n < 4; ++n)
          s[m][n] = __builtin_amdgcn_mfma_f32_16x16x32_bf16(qf[m][kk], kf[n],
                                                            s[m][n], 0, 0, 0);
    }

    // ---- online softmax (rows = m*16 + lg*4 + j; 16-lane butterfly) ----
    asm volatile("s_waitcnt lgkmcnt(0)" ::: "memory");  // prior-tile P reads done
#pragma unroll
    for (int m = 0; m < 2; ++m) {
#pragma unroll
      for (int n = 0; n < 4; ++n) s[m][n] *= SC;
#pragma unroll
      for (int j = 0; j < 4; ++j) {
        float tm = fmaxf(fmaxf(s[m][0][j], s[m][1][j]),
                         fmaxf(s[m][2][j], s[m][3][j]));
        tm = fmaxf(tm, __shfl_xor(tm, 1));
        tm = fmaxf(tm, __shfl_xor(tm, 2));
        tm = fmaxf(tm, __shfl_xor(tm, 4));
        tm = fmaxf(tm, __shfl_xor(tm, 8));
        float nm = fmaxf(mrow[m][j], tm);
        float so = __builtin_amdgcn_exp2f(mrow[m][j] - nm);
        mrow[m][j] = nm;
        float rs = 0.f;
#pragma unroll
        for (int n = 0; n < 4; ++n) {
          float p = __builtin_amdgcn_exp2f(s[m][n][j] - nm);
          rs += p;
          Pw[(m * 16 + lg * 4 + j) * 72 + n * 16 + lc] = f2bf(p);
        }
        rs += __shfl_xor(rs, 1);
        rs += __shfl_xor(rs, 2);
        rs += __shfl_xor(rs, 4);
        rs += __shfl_xor(rs, 8);
        lrow[m][j] = lrow[m][j] * so + rs;
#pragma unroll
        for (int nd = 0; nd < 4; ++nd) oacc[m][nd][j] *= so;
      }
    }
    asm volatile("s_waitcnt lgkmcnt(0)" ::: "memory");  // P writes visible
    __builtin_amdgcn_sched_barrier(0);

    // ---- O += P @ V ----
#pragma unroll
    for (int ks = 0; ks < 2; ++ks) {
      bf16x8 pf[2], vf[4];
#pragma unroll
      for (int m = 0; m < 2; ++m)
        pf[m] = *(const bf16x8*)((const char*)Pw + (m * 16 + lc) * 144 +
                                 lg * 16 + ks * 64);
#pragma unroll
      for (int nd = 0; nd < 4; ++nd)
        vf[nd] = *(const bf16x8*)((const char*)Vt + (nd * 16 + lc) * 144 +
                                  lg * 16 + ks * 64);
#pragma unroll
      for (int m = 0; m < 2; ++m)
#pragma unroll
        for (int nd = 0; nd < 4; ++nd)
          oacc[m][nd] = __builtin_amdgcn_mfma_f32_16x16x32_bf16(pf[m], vf[nd],
                                                                oacc[m][nd], 0, 0, 0);
    }

    __syncthreads();                    // all waves done with Ks/Vt
    if (kt < 31) {
      stage_kv(Kg, Vg, Ks, Vt, kt + 1, t);
      __syncthreads();                  // staged tile visible
    }
  }

  // ---- epilogue: divide by l, write [4096][1024] bf16 ----
  const size_t obase = (size_t)(b * 2048 + qt * 128 + w * 32);
#pragma unroll
  for (int m = 0; m < 2; ++m)
#pragma unroll
    for (int j = 0; j < 4; ++j) {
      float inv = 1.f / lrow[m][j];
      size_t r = (obase + m * 16 + lg * 4 + j) * 1024 + h * 64;
#pragma unroll
      for (int nd = 0; nd < 4; ++nd)
        aout[r + nd * 16 + lc] = f2bf(oacc[m][nd][j] * inv);
    }
}

// ---------------------------------------------------------------------------
extern "C" void kernel_launch(void* const* d_in, const int* in_sizes, int n_in,
                              void* d_out, int out_size, void* d_ws, size_t ws_size,
                              hipStream_t stream) {
  const float* x     = (const float*)d_in[0];   // [2,2048,1024] fp32
  const float* Wqkv  = (const float*)d_in[1];   // [3072,1024] fp32
  const float* Wproj = (const float*)d_in[2];   // [1024,1024] fp32
  const float* bproj = (const float*)d_in[3];   // [1024] fp32
  float* out = (float*)d_out;                   // [4096,1024] fp32

  ushort_t* qkv   = (ushort_t*)d_ws;                    // [4096,3072] bf16
  ushort_t* aout  = qkv   + (size_t)4096 * 3072;        // [4096,1024] bf16
  ushort_t* xb    = aout  + (size_t)4096 * 1024;        // [4096,1024] bf16
  ushort_t* wqb   = xb    + (size_t)4096 * 1024;        // [3072,1024] bf16
  ushort_t* wpb   = wqb   + (size_t)3072 * 1024;        // [1024,1024] bf16

  dim3 blk(256);
  // fp32 -> bf16 converts
  f2b_kernel<<<1024, blk, 0, stream>>>(x,     xb,  4096 * 1024 / 4);
  f2b_kernel<<<1024, blk, 0, stream>>>(Wqkv,  wqb, 3072 * 1024 / 4);
  f2b_kernel<<<512,  blk, 0, stream>>>(Wproj, wpb, 1024 * 1024 / 4);

  gemm_bt<false, ushort_t><<<dim3(24, 32), blk, 0, stream>>>(
      xb, wqb, nullptr, qkv, 4096, 3072, 1024);
  attn_fwd<<<dim3(16, 32), blk, 0, stream>>>(qkv, aout);
  gemm_bt<true, float><<<dim3(8, 32), blk, 0, stream>>>(
      aout, wpb, bproj, out, 4096, 1024, 1024);
}

// Round 4
// 174.602 us; speedup vs baseline: 1.1164x; 1.1164x over previous
//
#include <hip/hip_runtime.h>
#include <stdint.h>

typedef unsigned short ushort_t;
typedef __bf16 bf16x4 __attribute__((ext_vector_type(4)));
typedef __bf16 bf16x8 __attribute__((ext_vector_type(8)));
typedef float f32x4 __attribute__((ext_vector_type(4)));
typedef unsigned short us8 __attribute__((ext_vector_type(8)));
typedef unsigned short us4v __attribute__((ext_vector_type(4)));

__device__ __forceinline__ float bf2f(ushort_t u) {
  union { uint32_t u; float f; } v; v.u = ((uint32_t)u) << 16; return v.f;
}
__device__ __forceinline__ ushort_t f2bf(float f) {
  union { float f; uint32_t u; } v; v.f = f;
  uint32_t u = v.u;
  uint32_t r = (u + 0x7FFFu + ((u >> 16) & 1u)) >> 16;  // RNE
  return (ushort_t)r;
}
__device__ __forceinline__ void gload_lds16(const void* g, void* l) {
  __builtin_amdgcn_global_load_lds(
      (const __attribute__((address_space(1))) void*)g,
      (__attribute__((address_space(3))) void*)l, 16, 0, 0);
}
// ds_read_b64_tr_b16 (cross-lane transpose): each lane reads its OWN 8B
// qword at addr(l); HW delivers lane l column (l&15) of the [4][16] bf16
// tile formed by the 16-lane group's qwords in lane order. Correct pattern:
// addr(l) = subtile_base + (l&15)*8 bytes, subtile = [4 kv][16 d] row-major.
__device__ __forceinline__ void tr2(const ushort_t* p, bf16x4& lo, bf16x4& hi) {
  asm volatile("ds_read_b64_tr_b16 %0, %2\n\t"
               "ds_read_b64_tr_b16 %1, %2 offset:128"
               : "=&v"(lo), "=&v"(hi)
               : "v"((const __attribute__((address_space(3))) ushort_t*)p));
}

template <typename T> __device__ __forceinline__ T to_out(float f);
template <> __device__ __forceinline__ ushort_t to_out<ushort_t>(float f) { return f2bf(f); }
template <> __device__ __forceinline__ float to_out<float>(float f) { return f; }

// ---------------------------------------------------------------------------
// fp32 -> bf16 convert (vectorized, grid-stride)
// ---------------------------------------------------------------------------
__global__ void f2b_kernel(const float* __restrict__ in, ushort_t* __restrict__ out, int n4) {
  int i = blockIdx.x * blockDim.x + threadIdx.x;
  int stride = gridDim.x * blockDim.x;
  for (; i < n4; i += stride) {
    float4 v = ((const float4*)in)[i];
    us4v o;
    o[0] = f2bf(v.x); o[1] = f2bf(v.y); o[2] = f2bf(v.z); o[3] = f2bf(v.w);
    ((us4v*)out)[i] = o;
  }
}

// ---------------------------------------------------------------------------
// GEMM: C[M][N] = A[M][K] @ W[N][K]^T (+bias), bf16 in, fp32 accum, OT out.
// (unchanged from passing round-2 kernel)
// ---------------------------------------------------------------------------
template<bool BIAS, typename OT>
__global__ __launch_bounds__(256, 2) void gemm_bt(
    const ushort_t* __restrict__ A, const ushort_t* __restrict__ W,
    const float* __restrict__ bias, OT* __restrict__ C,
    int M, int N, int K)
{
  __shared__ ushort_t As[128 * 64];
  __shared__ ushort_t Bs[128 * 64];
  const int t = threadIdx.x;
  const int w = t >> 6, lane = t & 63;
  const int lg = lane >> 4, lc = lane & 15;
  const int rowbase = blockIdx.y * 128;
  const int colbase = blockIdx.x * 128;
  const int wr = (w >> 1) * 64, wc = (w & 1) * 64;

  f32x4 acc[4][4] = {};
  const int nkt = K >> 6;

  for (int kt = 0; kt < nkt; ++kt) {
#pragma unroll
    for (int i = 0; i < 4; ++i) {
      int off = (i * 256 + t) * 16;
      int row = off >> 7;
      int cb  = off & 127;
      int ec  = cb ^ ((row & 7) << 4);
      gload_lds16(A + (size_t)(rowbase + row) * K + kt * 64 + (ec >> 1),
                  (char*)As + off);
      gload_lds16(W + (size_t)(colbase + row) * K + kt * 64 + (ec >> 1),
                  (char*)Bs + off);
    }
    __syncthreads();
#pragma unroll
    for (int kk = 0; kk < 2; ++kk) {
      bf16x8 af[4], bf[4];
#pragma unroll
      for (int m = 0; m < 4; ++m) {
        int row = wr + m * 16 + lc;
        int kb  = (lg * 16 + kk * 64) ^ ((row & 7) << 4);
        af[m] = *(const bf16x8*)((const char*)As + row * 128 + kb);
        int col = wc + m * 16 + lc;
        int kb2 = (lg * 16 + kk * 64) ^ ((col & 7) << 4);
        bf[m] = *(const bf16x8*)((const char*)Bs + col * 128 + kb2);
      }
#pragma unroll
      for (int m = 0; m < 4; ++m)
#pragma unroll
        for (int n = 0; n < 4; ++n)
          acc[m][n] = __builtin_amdgcn_mfma_f32_16x16x32_bf16(af[m], bf[n],
                                                              acc[m][n], 0, 0, 0);
    }
    __syncthreads();
  }

#pragma unroll
  for (int m = 0; m < 4; ++m) {
    int r0 = rowbase + wr + m * 16 + lg * 4;
#pragma unroll
    for (int n = 0; n < 4; ++n) {
      int c0 = colbase + wc + n * 16 + lc;
      float bv = 0.f;
      if (BIAS) bv = bias[c0];
#pragma unroll
      for (int j = 0; j < 4; ++j)
        C[(size_t)(r0 + j) * N + c0] = to_out<OT>(acc[m][n][j] + bv);
    }
  }
}

// ---------------------------------------------------------------------------
// Flash attention v2: 512 threads (8 waves), 16 q-rows/wave, KVBLK=64,
// double-buffered K/V, tr_b16 V reads.
// qkv: [4096][3072] bf16; aout: [4096][1024] bf16.
// K LDS: [64][64] XOR-swizzled rows (as GEMM).
// V LDS: subtiled [d16=4][kv4=16][4][16] so B-frag = 2x ds_read_b64_tr_b16.
// ---------------------------------------------------------------------------
__global__ __launch_bounds__(512, 4) void attn_fwd(
    const ushort_t* __restrict__ qkv, ushort_t* __restrict__ aout)
{
  __shared__ ushort_t Ks[2][64 * 64];
  __shared__ ushort_t Vs[2][64 * 64];
  __shared__ ushort_t Ps[8][16 * 72];

  const int t = threadIdx.x, w = t >> 6, lane = t & 63;
  const int lg = lane >> 4, lc = lane & 15;
  const int qt = blockIdx.x, bh = blockIdx.y;
  const int b = bh >> 4, h = bh & 15;

  const ushort_t* Qg = qkv + (size_t)(b * 2048) * 3072 + h * 64;
  const ushort_t* Kg = Qg + 1024;
  const ushort_t* Vg = Qg + 2048;

  // ---- staging helpers (512 threads) ----
  // K tile: one 16B gload_lds per thread, XOR-preswizzled source
  auto stage_k = [&](ushort_t* Kd, int kt) {
    int off = t * 16;
    int row = off >> 7;
    int cb  = off & 127;
    int ec  = cb ^ ((row & 7) << 4);
    gload_lds16(Kg + (size_t)(kt * 64 + row) * 3072 + (ec >> 1),
                (char*)Kd + off);
  };
  const int vr  = t >> 3;           // kv row this thread stages
  const int vc0 = (t & 7) * 8;      // d base
  // dest byte addr in subtiled layout [d16][kv4][4][16]
  const int vdst = (vc0 >> 4) * 2048 + (vr >> 2) * 128 + (vr & 3) * 32 + (vc0 & 8) * 2;

  // ---- Q fragments straight from global (read-once) ----
  bf16x8 qf[2];
#pragma unroll
  for (int kk = 0; kk < 2; ++kk)
    qf[kk] = *(const bf16x8*)(Qg + (size_t)(qt * 128 + w * 16 + lc) * 3072 +
                              kk * 32 + lg * 8);

  stage_k(Ks[0], 0);
  {
    us8 v = *(const us8*)(Vg + (size_t)vr * 3072 + vc0);
    *(us8*)((char*)Vs[0] + vdst) = v;
  }
  __syncthreads();

  f32x4 oacc[4] = {};
  float mrow[4], lrow[4];
#pragma unroll
  for (int j = 0; j < 4; ++j) { mrow[j] = -INFINITY; lrow[j] = 0.f; }

  ushort_t* Pw = &Ps[w][0];
  const float SC = 0.125f * 1.44269504088896f;  // scale * log2(e)

  int cur = 0;
  for (int kt = 0; kt < 32; ++kt) {
    // ---- issue next tile's loads early (hide under QK+softmax) ----
    us8 vnext;
    if (kt < 31) {
      stage_k(Ks[cur ^ 1], kt + 1);
      vnext = *(const us8*)(Vg + (size_t)((kt + 1) * 64 + vr) * 3072 + vc0);
    }

    // ---- S = Q @ K^T (wave: 16 q-rows x 64 kv) ----
    const ushort_t* Kc = Ks[cur];
    f32x4 s[4] = {};
#pragma unroll
    for (int kk = 0; kk < 2; ++kk) {
      bf16x8 kf[4];
#pragma unroll
      for (int n = 0; n < 4; ++n) {
        int row = n * 16 + lc;
        int kb  = (lg * 16 + kk * 64) ^ ((row & 7) << 4);
        kf[n] = *(const bf16x8*)((const char*)Kc + row * 128 + kb);
      }
#pragma unroll
      for (int n = 0; n < 4; ++n)
        s[n] = __builtin_amdgcn_mfma_f32_16x16x32_bf16(qf[kk], kf[n], s[n], 0, 0, 0);
    }

    // ---- online softmax; rows = lg*4+j, 16-lane (lc) butterfly ----
#pragma unroll
    for (int n = 0; n < 4; ++n) s[n] *= SC;
#pragma unroll
    for (int j = 0; j < 4; ++j) {
      float tm = fmaxf(fmaxf(s[0][j], s[1][j]), fmaxf(s[2][j], s[3][j]));
      tm = fmaxf(tm, __shfl_xor(tm, 1));
      tm = fmaxf(tm, __shfl_xor(tm, 2));
      tm = fmaxf(tm, __shfl_xor(tm, 4));
      tm = fmaxf(tm, __shfl_xor(tm, 8));
      float nm = fmaxf(mrow[j], tm);
      float so = __builtin_amdgcn_exp2f(mrow[j] - nm);
      mrow[j] = nm;
      float rs = 0.f;
#pragma unroll
      for (int n = 0; n < 4; ++n) {
        float p = __builtin_amdgcn_exp2f(s[n][j] - nm);
        rs += p;
        Pw[(lg * 4 + j) * 72 + n * 16 + lc] = f2bf(p);
      }
      rs += __shfl_xor(rs, 1);
      rs += __shfl_xor(rs, 2);
      rs += __shfl_xor(rs, 4);
      rs += __shfl_xor(rs, 8);
      lrow[j] = lrow[j] * so + rs;
#pragma unroll
      for (int nd = 0; nd < 4; ++nd) oacc[nd][j] *= so;
    }

    // ---- write next V tile to LDS (vmcnt wait lands here, hidden) ----
    if (kt < 31) *(us8*)((char*)Vs[cur ^ 1] + vdst) = vnext;

    // ---- O += P @ V : A-frags from own Ps, B-frags via tr reads ----
    const ushort_t* Vc = Vs[cur];
    bf16x8 pf[2], vf[2][4];
#pragma unroll
    for (int ks = 0; ks < 2; ++ks) {
      pf[ks] = *(const bf16x8*)((const char*)Pw + lc * 144 + ks * 64 + lg * 16);
#pragma unroll
      for (int nd = 0; nd < 4; ++nd) {
        bf16x4 lo, hi;
        // subtile base (elements) + lane's own qword: lc*4 elems = lc*8 bytes
        tr2(Vc + nd * 1024 + (ks * 8 + lg * 2) * 64 + lc * 4, lo, hi);
        vf[ks][nd] = __builtin_shufflevector(lo, hi, 0, 1, 2, 3, 4, 5, 6, 7);
      }
    }
    asm volatile("s_waitcnt lgkmcnt(0)" ::: "memory");  // rule #18
    __builtin_amdgcn_sched_barrier(0);
#pragma unroll
    for (int ks = 0; ks < 2; ++ks)
#pragma unroll
      for (int nd = 0; nd < 4; ++nd)
        oacc[nd] = __builtin_amdgcn_mfma_f32_16x16x32_bf16(pf[ks], vf[ks][nd],
                                                           oacc[nd], 0, 0, 0);

    __syncthreads();   // drains staging (vm+lgkm) & protects buffers
    cur ^= 1;
  }

  // ---- epilogue ----
  const size_t obase = (size_t)(b * 2048 + qt * 128 + w * 16);
#pragma unroll
  for (int j = 0; j < 4; ++j) {
    float inv = 1.f / lrow[j];
    size_t r = (obase + lg * 4 + j) * 1024 + h * 64;
#pragma unroll
    for (int nd = 0; nd < 4; ++nd)
      aout[r + nd * 16 + lc] = f2bf(oacc[nd][j] * inv);
  }
}

// ---------------------------------------------------------------------------
extern "C" void kernel_launch(void* const* d_in, const int* in_sizes, int n_in,
                              void* d_out, int out_size, void* d_ws, size_t ws_size,
                              hipStream_t stream) {
  const float* x     = (const float*)d_in[0];   // [2,2048,1024] fp32
  const float* Wqkv  = (const float*)d_in[1];   // [3072,1024] fp32
  const float* Wproj = (const float*)d_in[2];   // [1024,1024] fp32
  const float* bproj = (const float*)d_in[3];   // [1024] fp32
  float* out = (float*)d_out;                   // [4096,1024] fp32

  ushort_t* qkv   = (ushort_t*)d_ws;                    // [4096,3072] bf16
  ushort_t* aout  = qkv   + (size_t)4096 * 3072;        // [4096,1024] bf16
  ushort_t* xb    = aout  + (size_t)4096 * 1024;        // [4096,1024] bf16
  ushort_t* wqb   = xb    + (size_t)4096 * 1024;        // [3072,1024] bf16
  ushort_t* wpb   = wqb   + (size_t)3072 * 1024;        // [1024,1024] bf16

  dim3 blk(256);
  f2b_kernel<<<1024, blk, 0, stream>>>(x,     xb,  4096 * 1024 / 4);
  f2b_kernel<<<1024, blk, 0, stream>>>(Wqkv,  wqb, 3072 * 1024 / 4);
  f2b_kernel<<<512,  blk, 0, stream>>>(Wproj, wpb, 1024 * 1024 / 4);

  gemm_bt<false, ushort_t><<<dim3(24, 32), blk, 0, stream>>>(
      xb, wqb, nullptr, qkv, 4096, 3072, 1024);
  attn_fwd<<<dim3(16, 32), dim3(512), 0, stream>>>(qkv, aout);
  gemm_bt<true, float><<<dim3(8, 32), blk, 0, stream>>>(
      aout, wpb, bproj, out, 4096, 1024, 1024);
}

// Round 5
// 125.713 us; speedup vs baseline: 1.5506x; 1.3889x over previous
//
#include <hip/hip_runtime.h>
#include <stdint.h>

typedef unsigned short ushort_t;
typedef __bf16 bf16x4 __attribute__((ext_vector_type(4)));
typedef __bf16 bf16x8 __attribute__((ext_vector_type(8)));
typedef float f32x4 __attribute__((ext_vector_type(4)));
typedef float f32x16 __attribute__((ext_vector_type(16)));
typedef unsigned short us8 __attribute__((ext_vector_type(8)));
typedef unsigned short us4v __attribute__((ext_vector_type(4)));

__device__ __forceinline__ float bf2f(ushort_t u) {
  union { uint32_t u; float f; } v; v.u = ((uint32_t)u) << 16; return v.f;
}
__device__ __forceinline__ ushort_t f2bf(float f) {
  union { float f; uint32_t u; } v; v.f = f;
  uint32_t u = v.u;
  uint32_t r = (u + 0x7FFFu + ((u >> 16) & 1u)) >> 16;  // RNE
  return (ushort_t)r;
}
__device__ __forceinline__ uint32_t pkbf(float a, float b) {
  __bf16 x = (__bf16)a, y = (__bf16)b;           // native RNE converts
  uint32_t ux = __builtin_bit_cast(unsigned short, x);
  uint32_t uy = __builtin_bit_cast(unsigned short, y);
  return ux | (uy << 16);
}
__device__ __forceinline__ void gload_lds16(const void* g, void* l) {
  __builtin_amdgcn_global_load_lds(
      (const __attribute__((address_space(1))) void*)g,
      (__attribute__((address_space(3))) void*)l, 16, 0, 0);
}
// ds_read_b64_tr_b16 (cross-lane transpose): 16-lane group, lane reads its
// own qword at base+(l&15)*8; delivers column (l&15) of the [4kv][16d] subtile.
__device__ __forceinline__ void tr2(const ushort_t* p, bf16x4& lo, bf16x4& hi) {
  asm volatile("ds_read_b64_tr_b16 %0, %2\n\t"
               "ds_read_b64_tr_b16 %1, %2 offset:128"
               : "=&v"(lo), "=&v"(hi)
               : "v"((const __attribute__((address_space(3))) ushort_t*)p));
}

template <typename T> __device__ __forceinline__ T to_out(float f);
template <> __device__ __forceinline__ ushort_t to_out<ushort_t>(float f) { return f2bf(f); }
template <> __device__ __forceinline__ float to_out<float>(float f) { return f; }

// ---------------------------------------------------------------------------
// fp32 -> bf16 convert (vectorized, grid-stride)
// ---------------------------------------------------------------------------
__global__ void f2b_kernel(const float* __restrict__ in, ushort_t* __restrict__ out, int n4) {
  int i = blockIdx.x * blockDim.x + threadIdx.x;
  int stride = gridDim.x * blockDim.x;
  for (; i < n4; i += stride) {
    float4 v = ((const float4*)in)[i];
    us4v o;
    o[0] = f2bf(v.x); o[1] = f2bf(v.y); o[2] = f2bf(v.z); o[3] = f2bf(v.w);
    ((us4v*)out)[i] = o;
  }
}

// ---------------------------------------------------------------------------
// GEMM: C[M][N] = A[M][K] @ W[N][K]^T (+bias)  (unchanged, proven)
// ---------------------------------------------------------------------------
template<bool BIAS, typename OT>
__global__ __launch_bounds__(256, 2) void gemm_bt(
    const ushort_t* __restrict__ A, const ushort_t* __restrict__ W,
    const float* __restrict__ bias, OT* __restrict__ C,
    int M, int N, int K)
{
  __shared__ ushort_t As[128 * 64];
  __shared__ ushort_t Bs[128 * 64];
  const int t = threadIdx.x;
  const int w = t >> 6, lane = t & 63;
  const int lg = lane >> 4, lc = lane & 15;
  const int rowbase = blockIdx.y * 128;
  const int colbase = blockIdx.x * 128;
  const int wr = (w >> 1) * 64, wc = (w & 1) * 64;

  f32x4 acc[4][4] = {};
  const int nkt = K >> 6;

  for (int kt = 0; kt < nkt; ++kt) {
#pragma unroll
    for (int i = 0; i < 4; ++i) {
      int off = (i * 256 + t) * 16;
      int row = off >> 7;
      int cb  = off & 127;
      int ec  = cb ^ ((row & 7) << 4);
      gload_lds16(A + (size_t)(rowbase + row) * K + kt * 64 + (ec >> 1),
                  (char*)As + off);
      gload_lds16(W + (size_t)(colbase + row) * K + kt * 64 + (ec >> 1),
                  (char*)Bs + off);
    }
    __syncthreads();
#pragma unroll
    for (int kk = 0; kk < 2; ++kk) {
      bf16x8 af[4], bf[4];
#pragma unroll
      for (int m = 0; m < 4; ++m) {
        int row = wr + m * 16 + lc;
        int kb  = (lg * 16 + kk * 64) ^ ((row & 7) << 4);
        af[m] = *(const bf16x8*)((const char*)As + row * 128 + kb);
        int col = wc + m * 16 + lc;
        int kb2 = (lg * 16 + kk * 64) ^ ((col & 7) << 4);
        bf[m] = *(const bf16x8*)((const char*)Bs + col * 128 + kb2);
      }
#pragma unroll
      for (int m = 0; m < 4; ++m)
#pragma unroll
        for (int n = 0; n < 4; ++n)
          acc[m][n] = __builtin_amdgcn_mfma_f32_16x16x32_bf16(af[m], bf[n],
                                                              acc[m][n], 0, 0, 0);
    }
    __syncthreads();
  }

#pragma unroll
  for (int m = 0; m < 4; ++m) {
    int r0 = rowbase + wr + m * 16 + lg * 4;
#pragma unroll
    for (int n = 0; n < 4; ++n) {
      int c0 = colbase + wc + n * 16 + lc;
      float bv = 0.f;
      if (BIAS) bv = bias[c0];
#pragma unroll
      for (int j = 0; j < 4; ++j)
        C[(size_t)(r0 + j) * N + c0] = to_out<OT>(acc[m][n][j] + bv);
    }
  }
}

// ---------------------------------------------------------------------------
// Flash attention v3: swapped-QK in-register softmax (m214/§B structure).
// 256 threads = 4 waves, 32 q-rows/wave (q-tile 128), KVBLK=64, 32x32x16 MFMA.
// S^T = mfma(K,Q): lane holds S[kv=crow(r,hi)][q=lane&31]; softmax in-lane +
// one shfl_xor(32); P repacked via v_permlane32_swap; PV B-frags via tr_read.
// K LDS [64][64] XOR-swizzled; V LDS subtiled [d16=4][kv4=16][4][16].
// ---------------------------------------------------------------------------
__global__ __launch_bounds__(256, 2) void attn_fwd(
    const ushort_t* __restrict__ qkv, ushort_t* __restrict__ aout)
{
  __shared__ ushort_t Ks[2][64 * 64];
  __shared__ ushort_t Vs[2][64 * 64];

  const int t = threadIdx.x, w = t >> 6, lane = t & 63;
  const int l31 = lane & 31, hi = lane >> 5;
  const int lc = lane & 15;

  // XCD-aware decode: xcd = d&7 gets bh block xcd*4 + d>>7 -> K/V L2-resident
  const int d = blockIdx.x;
  const int qt = (d >> 3) & 15;
  const int bh = (d & 7) * 4 + (d >> 7);
  const int b = bh >> 4, h = bh & 15;

  const ushort_t* Qg = qkv + (size_t)(b * 2048) * 3072 + h * 64;
  const ushort_t* Kg = Qg + 1024;
  const ushort_t* Vg = Qg + 2048;

  auto stage_k = [&](ushort_t* Kd, int kt) {
#pragma unroll
    for (int i = 0; i < 2; ++i) {
      int off = (i * 256 + t) * 16;
      int row = off >> 7;
      int cb  = off & 127;
      int ec  = cb ^ ((row & 7) << 4);
      gload_lds16(Kg + (size_t)(kt * 64 + row) * 3072 + (ec >> 1),
                  (char*)Kd + off);
    }
  };
  // V stage dest (round-4-verified subtiled layout)
  int vr[2], vc0[2], vdst[2];
#pragma unroll
  for (int i = 0; i < 2; ++i) {
    int u = i * 256 + t;
    vr[i]  = u >> 3;
    vc0[i] = (u & 7) * 8;
    vdst[i] = (vc0[i] >> 4) * 2048 + (vr[i] >> 2) * 128 + (vr[i] & 3) * 32 +
              (vc0[i] & 8) * 2;
  }

  // ---- Q fragments (B-operand): lane -> Q[q=l31][d = kk*16+hi*8+e] ----
  const ushort_t* qrow_p = Qg + (size_t)(qt * 128 + w * 32 + l31) * 3072;
  bf16x8 qf[4];
#pragma unroll
  for (int kk = 0; kk < 4; ++kk)
    qf[kk] = *(const bf16x8*)(qrow_p + kk * 16 + hi * 8);

  // ---- prologue staging ----
  stage_k(Ks[0], 0);
#pragma unroll
  for (int i = 0; i < 2; ++i) {
    us8 v = *(const us8*)(Vg + (size_t)vr[i] * 3072 + vc0[i]);
    *(us8*)((char*)Vs[0] + vdst[i]) = v;
  }
  __syncthreads();

  f32x16 oacc0 = {}, oacc1 = {};
  float m = -1e30f, l = 0.f;
  const float SC = 0.125f * 1.44269504088896f;  // scale * log2(e)

  int cur = 0;
  for (int kt = 0; kt < 32; ++kt) {
    // ---- issue next tile's loads early ----
    us8 vnext[2];
    if (kt < 31) {
      stage_k(Ks[cur ^ 1], kt + 1);
#pragma unroll
      for (int i = 0; i < 2; ++i)
        vnext[i] = *(const us8*)(Vg + (size_t)((kt + 1) * 64 + vr[i]) * 3072 + vc0[i]);
    }

    // ---- S^T = K @ Q^T : s0 = kv 0..31, s1 = kv 32..63 (cols = q) ----
    const ushort_t* Kc = Ks[cur];
    f32x16 s0 = {}, s1 = {};
#pragma unroll
    for (int kk = 0; kk < 4; ++kk) {
      int cbyte = (kk * 32 + hi * 16);
      int r0 = l31, r1 = 32 + l31;
      bf16x8 kf0 = *(const bf16x8*)((const char*)Kc + r0 * 128 +
                                    (cbyte ^ ((r0 & 7) << 4)));
      bf16x8 kf1 = *(const bf16x8*)((const char*)Kc + r1 * 128 +
                                    (cbyte ^ ((r1 & 7) << 4)));
      s0 = __builtin_amdgcn_mfma_f32_32x32x16_bf16(kf0, qf[kk], s0, 0, 0, 0);
      s1 = __builtin_amdgcn_mfma_f32_32x32x16_bf16(kf1, qf[kk], s1, 0, 0, 0);
    }

    // ---- in-register online softmax for q = l31 ----
    float tm = fmaxf(s0[0], s1[0]);
#pragma unroll
    for (int i = 1; i < 16; ++i) tm = fmaxf(tm, fmaxf(s0[i], s1[i]));
    tm = fmaxf(tm, __shfl_xor(tm, 32));
    float tms = tm * SC;
    if (__any(tms > m + 8.f)) {            // defer-max: rare (kt==0 only)
      float nm = fmaxf(m, tms);
      float so = __builtin_amdgcn_exp2f(m - nm);
      m = nm; l *= so;
#pragma unroll
      for (int r = 0; r < 16; ++r) {
        float sor = __shfl(so, (r & 3) + 8 * (r >> 2) + 4 * hi);
        oacc0[r] *= sor; oacc1[r] *= sor;
      }
    }
#pragma unroll
    for (int i = 0; i < 16; ++i) {
      s0[i] = __builtin_amdgcn_exp2f(__builtin_fmaf(s0[i], SC, -m));
      s1[i] = __builtin_amdgcn_exp2f(__builtin_fmaf(s1[i], SC, -m));
    }
    float rs = 0.f;
#pragma unroll
    for (int i = 0; i < 16; ++i) rs += s0[i] + s1[i];
    rs += __shfl_xor(rs, 32);
    l += rs;

    // ---- P -> bf16 dwords (pairs of consecutive r) ----
    uint32_t pk0[8], pk1[8];
#pragma unroll
    for (int j = 0; j < 8; ++j) {
      pk0[j] = pkbf(s0[2 * j], s0[2 * j + 1]);
      pk1[j] = pkbf(s1[2 * j], s1[2 * j + 1]);
    }

    // ---- write next V tile ----
    if (kt < 31) {
#pragma unroll
      for (int i = 0; i < 2; ++i)
        *(us8*)((char*)Vs[cur ^ 1] + vdst[i]) = vnext[i];
    }

    // ---- build PV operands: pa via permlane32_swap, vf via tr_read ----
    const ushort_t* Vc = Vs[cur];
    bf16x8 pa[4], vf[4][2];
#pragma unroll
    for (int ks = 0; ks < 4; ++ks) {
      int j0 = 4 * (ks & 1);
      uint32_t x0 = (ks < 2) ? pk0[j0]     : pk1[j0];
      uint32_t x1 = (ks < 2) ? pk0[j0 + 1] : pk1[j0 + 1];
      uint32_t y0 = (ks < 2) ? pk0[j0 + 2] : pk1[j0 + 2];
      uint32_t y1 = (ks < 2) ? pk0[j0 + 3] : pk1[j0 + 3];
      asm volatile("v_permlane32_swap_b32 %0, %1" : "+v"(x0), "+v"(y0));
      asm volatile("v_permlane32_swap_b32 %0, %1" : "+v"(x1), "+v"(y1));
      union { uint32_t du[4]; bf16x8 v; } U;
      U.du[0] = x0; U.du[1] = x1; U.du[2] = y0; U.du[3] = y1;
      pa[ks] = U.v;
      const int m16 = (lane >> 4) & 1;
#pragma unroll
      for (int nd = 0; nd < 2; ++nd) {
        bf16x4 lo, hh;
        tr2(Vc + (nd * 2 + m16) * 1024 + (4 * ks + 2 * hi) * 64 + lc * 4, lo, hh);
        vf[ks][nd] = __builtin_shufflevector(lo, hh, 0, 1, 2, 3, 4, 5, 6, 7);
      }
    }
    asm volatile("s_waitcnt lgkmcnt(0)" ::: "memory");  // rule #18
    __builtin_amdgcn_sched_barrier(0);
#pragma unroll
    for (int ks = 0; ks < 4; ++ks) {
      oacc0 = __builtin_amdgcn_mfma_f32_32x32x16_bf16(pa[ks], vf[ks][0], oacc0, 0, 0, 0);
      oacc1 = __builtin_amdgcn_mfma_f32_32x32x16_bf16(pa[ks], vf[ks][1], oacc1, 0, 0, 0);
    }

    __syncthreads();   // drains staging; protects double buffers
    cur ^= 1;
  }

  // ---- epilogue: O[q=crow(r,hi)][d=nd*32+l31] / l ----
  float inv = 1.f / l;
#pragma unroll
  for (int r = 0; r < 16; ++r) {
    int crow = (r & 3) + 8 * (r >> 2) + 4 * hi;
    float iq = __shfl(inv, crow);
    int qrow = qt * 128 + w * 32 + crow;
    size_t base = ((size_t)(b * 2048 + qrow)) * 1024 + h * 64 + l31;
    aout[base]      = f2bf(oacc0[r] * iq);
    aout[base + 32] = f2bf(oacc1[r] * iq);
  }
}

// ---------------------------------------------------------------------------
extern "C" void kernel_launch(void* const* d_in, const int* in_sizes, int n_in,
                              void* d_out, int out_size, void* d_ws, size_t ws_size,
                              hipStream_t stream) {
  const float* x     = (const float*)d_in[0];   // [2,2048,1024] fp32
  const float* Wqkv  = (const float*)d_in[1];   // [3072,1024] fp32
  const float* Wproj = (const float*)d_in[2];   // [1024,1024] fp32
  const float* bproj = (const float*)d_in[3];   // [1024] fp32
  float* out = (float*)d_out;                   // [4096,1024] fp32

  ushort_t* qkv   = (ushort_t*)d_ws;                    // [4096,3072] bf16
  ushort_t* aout  = qkv   + (size_t)4096 * 3072;        // [4096,1024] bf16
  ushort_t* xb    = aout  + (size_t)4096 * 1024;        // [4096,1024] bf16
  ushort_t* wqb   = xb    + (size_t)4096 * 1024;        // [3072,1024] bf16
  ushort_t* wpb   = wqb   + (size_t)3072 * 1024;        // [1024,1024] bf16

  dim3 blk(256);
  f2b_kernel<<<1024, blk, 0, stream>>>(x,     xb,  4096 * 1024 / 4);
  f2b_kernel<<<1024, blk, 0, stream>>>(Wqkv,  wqb, 3072 * 1024 / 4);
  f2b_kernel<<<512,  blk, 0, stream>>>(Wproj, wpb, 1024 * 1024 / 4);

  gemm_bt<false, ushort_t><<<dim3(24, 32), blk, 0, stream>>>(
      xb, wqb, nullptr, qkv, 4096, 3072, 1024);
  attn_fwd<<<dim3(512), blk, 0, stream>>>(qkv, aout);
  gemm_bt<true, float><<<dim3(8, 32), blk, 0, stream>>>(
      aout, wpb, bproj, out, 4096, 1024, 1024);
}